// Round 5
// baseline (260.545 us; speedup 1.0000x reference)
//
#include <hip/hip_runtime.h>

typedef float f32x4 __attribute__((ext_vector_type(4)));
typedef short bf16x8 __attribute__((ext_vector_type(8)));
typedef short bf16x4 __attribute__((ext_vector_type(4)));

#define DEV __device__ __forceinline__

DEV unsigned short f2bf(float x) {
  union { float f; unsigned u; } v; v.f = x;
  unsigned r = v.u + 0x7fffu + ((v.u >> 16) & 1u);
  return (unsigned short)(r >> 16);
}
DEV float bf2f(unsigned short h) {
  union { unsigned u; float f; } v; v.u = ((unsigned)h) << 16;
  return v.f;
}

#if defined(__has_builtin)
# if __has_builtin(__builtin_amdgcn_global_load_lds)
#  define HAVE_GLL 1
# endif
# if __has_builtin(__builtin_amdgcn_exp2f)
#  define EXP2(x) __builtin_amdgcn_exp2f(x)
# else
#  define EXP2(x) exp2f(x)
# endif
#else
# define EXP2(x) exp2f(x)
#endif

// pack trunc-bf16(a) | trunc-bf16(b)<<16 in ONE v_perm_b32
DEV unsigned pk_bf16_trunc(float a, float b) {
  return __builtin_amdgcn_perm(__float_as_uint(b), __float_as_uint(a), 0x07060302u);
}
// rounded pack
DEV unsigned pk_bf16_rnd(float a, float b) {
  return ((unsigned)f2bf(b) << 16) | f2bf(a);
}

// 16B global->LDS. Per-wave: dest = uniform base + lane*16.
DEV void g2l16(const unsigned short* g, unsigned short* l) {
#ifdef HAVE_GLL
  __builtin_amdgcn_global_load_lds((const __attribute__((address_space(1))) void*)g,
                                   (__attribute__((address_space(3))) void*)l, 16, 0, 0);
#else
  *(uint4*)l = *(const uint4*)g;
#endif
}

DEV f32x4 mfma16x16x16(bf16x4 a, bf16x4 b, f32x4 c) {
#if defined(__has_builtin) && __has_builtin(__builtin_amdgcn_mfma_f32_16x16x16bf16_1k)
  return __builtin_amdgcn_mfma_f32_16x16x16bf16_1k(a, b, c, 0, 0, 0);
#else
  asm volatile("v_mfma_f32_16x16x16_bf16 %0, %1, %2, %0" : "+v"(c) : "v"(a), "v"(b));
  return c;
#endif
}

// ======== fused prep: rope table + x cast + both W transposes (one launch) ========
__global__ __launch_bounds__(256) void prep(const float* __restrict__ x,
                                            const float* __restrict__ Wqkv,
                                            const float* __restrict__ Wout,
                                            float* cosb, float* sinb,
                                            unsigned short* __restrict__ A1,
                                            unsigned short* __restrict__ W1t,
                                            unsigned short* __restrict__ W2t) {
  __shared__ float t[64 * 65];
  int blk = blockIdx.x;
  if (blk < 256) {
    int i = blk * 256 + threadIdx.x;
    int tt = i >> 5, d = i & 31;
    float invf = (float)(1.0 / pow(10000.0, (double)d / 32.0));
    float ang = (float)tt * invf;
    cosb[i] = (float)cos((double)ang);
    sinb[i] = (float)sin((double)ang);
    return;
  }
  if (blk < 4352) {
    int i = (blk - 256) * 256 + threadIdx.x;
    f32x4 v = ((const f32x4*)x)[i];
    ushort4 o;
    o.x = f2bf(v[0]); o.y = f2bf(v[1]); o.z = f2bf(v[2]); o.w = f2bf(v[3]);
    ((ushort4*)A1)[i] = o;
    return;
  }
  const float* W; unsigned short* Wt; int N, bidx;
  if (blk < 5120) { W = Wqkv; Wt = W1t; N = 3072; bidx = blk - 4352; }
  else            { W = Wout; Wt = W2t; N = 1024; bidx = blk - 5120; }
  int k0 = (bidx & 15) * 64, n0 = (bidx >> 4) * 64;
  for (int idx = threadIdx.x; idx < 4096; idx += 256) {
    int kl = idx >> 6, nl = idx & 63;
    t[kl * 65 + nl] = W[(size_t)(k0 + kl) * N + n0 + nl];
  }
  __syncthreads();
  for (int idx = threadIdx.x; idx < 4096; idx += 256) {
    int nl = idx >> 6, kl = idx & 63;
    Wt[(size_t)(n0 + nl) * 1024 + k0 + kl] = f2bf(t[kl * 65 + nl]);
  }
}

// ---------------- qkv GEMM + fused RoPE epilogue ----------------
// q/k heads stored with INTERLEAVED rotation pairs: head-block position 2*dr   = rope_lo(dr)
//                                                   head-block position 2*dr+1 = rope_hi(dr)
// (same permutation for q and k => q.k dot is unchanged; flash reads it opaquely)
#define QSCALE 0.180336880f   // 0.125 * log2(e)
__global__ __launch_bounds__(256, 2) void gemm_qkv(
    const unsigned short* __restrict__ A, const unsigned short* __restrict__ Bt,
    const float* __restrict__ bias, const float* __restrict__ cosb,
    const float* __restrict__ sinb, unsigned short* __restrict__ QK,
    unsigned short* __restrict__ Vt) {
  const int K = 1024;
  __shared__ alignas(16) unsigned short As[128 * 64];
  __shared__ alignas(16) unsigned short Bs[128 * 64];
  const int tid = threadIdx.x;
  const int lane = tid & 63, wave = tid >> 6;
  const int l15 = lane & 15, quad = lane >> 4;
  const int m0 = blockIdx.y * 128, n0 = blockIdx.x * 128;
  const int wm = (wave & 1) * 64, wn = (wave >> 1) * 64;

  f32x4 acc[4][4];
#pragma unroll
  for (int i = 0; i < 4; i++)
#pragma unroll
    for (int j = 0; j < 4; j++)
#pragma unroll
      for (int r = 0; r < 4; r++) acc[i][j][r] = 0.f;

  for (int kt = 0; kt < 16; ++kt) {
    __syncthreads();
#pragma unroll
    for (int i = 0; i < 4; ++i) {
      int u = i * 256 + tid;
      int row = u >> 3;
      int kcg = (u & 7) ^ (row & 7);
      g2l16(A  + (size_t)(m0 + row) * K + (kt << 6) + (kcg << 3), As + u * 8);
      g2l16(Bt + (size_t)(n0 + row) * K + (kt << 6) + (kcg << 3), Bs + u * 8);
    }
    __syncthreads();
#pragma unroll
    for (int ks = 0; ks < 2; ++ks) {
      const int kc = ks * 4 + quad;
      bf16x8 af[4], bfr[4];
#pragma unroll
      for (int t = 0; t < 4; ++t) {
        int mrow = wm + t * 16 + l15;
        af[t] = *(const bf16x8*)(As + (mrow * 8 + (kc ^ (mrow & 7))) * 8);
        int nrow = wn + t * 16 + l15;
        bfr[t] = *(const bf16x8*)(Bs + (nrow * 8 + (kc ^ (nrow & 7))) * 8);
      }
#pragma unroll
      for (int mt = 0; mt < 4; ++mt)
#pragma unroll
        for (int nt = 0; nt < 4; ++nt)
          acc[mt][nt] = __builtin_amdgcn_mfma_f32_16x16x32_bf16(af[mt], bfr[nt], acc[mt][nt], 0, 0, 0);
    }
  }
  // ---- epilogue: C/D layout col=lane&15, row=quad*4+reg ----
  const int headcol = n0 + wn;          // wave-uniform, multiple of 64
  const int b = m0 >> 11;
  float bb[4];
#pragma unroll
  for (int nt = 0; nt < 4; ++nt) bb[nt] = bias[headcol + nt * 16 + l15];

  if (headcol < 2048) {                 // q or k: RoPE in fp32, paired 4B stores
    const float scale = (headcol < 1024) ? QSCALE : 1.f;
#pragma unroll
    for (int mt = 0; mt < 4; ++mt) {
#pragma unroll
      for (int r = 0; r < 4; ++r) {
        int row = m0 + wm + mt * 16 + quad * 4 + r;
        int t = row & 2047;
#pragma unroll
        for (int nt = 0; nt < 2; ++nt) {
          int dr = nt * 16 + l15;       // 0..31
          float c = cosb[t * 32 + dr], s = sinb[t * 32 + dr];
          float v1 = acc[mt][nt][r] + bb[nt];
          float v2 = acc[mt][nt + 2][r] + bb[nt + 2];
          unsigned w = pk_bf16_rnd((v1 * c - v2 * s) * scale, (v2 * c + v1 * s) * scale);
          *(unsigned*)(QK + (size_t)row * 2048 + headcol + 2 * dr) = w;
        }
      }
    }
  } else {                              // v: write transposed [bh][d][t], pack 4 t per store
    const int hv = (headcol - 2048) >> 6;
    const int t0 = (m0 + wm) & 2047;
#pragma unroll
    for (int mt = 0; mt < 4; ++mt)
#pragma unroll
      for (int nt = 0; nt < 4; ++nt) {
        int d = nt * 16 + l15;
        uint2 w;
        w.x = pk_bf16_rnd(acc[mt][nt][0] + bb[nt], acc[mt][nt][1] + bb[nt]);
        w.y = pk_bf16_rnd(acc[mt][nt][2] + bb[nt], acc[mt][nt][3] + bb[nt]);
        *(uint2*)(Vt + ((size_t)((b * 16 + hv) * 64 + d)) * 2048 + t0 + mt * 16 + quad * 4) = w;
      }
  }
}

// ---------------- bf16 GEMM, 64(M)x128(N) tile (out-projection) ----------------
__global__ __launch_bounds__(256, 2) void gemm64(
    const unsigned short* __restrict__ A, const unsigned short* __restrict__ Bt,
    const float* __restrict__ bias, float* __restrict__ C, int M, int N, int K) {
  __shared__ alignas(16) unsigned short As[64 * 64];
  __shared__ alignas(16) unsigned short Bs[128 * 64];
  const int tid = threadIdx.x;
  const int lane = tid & 63, wave = tid >> 6;
  const int l15 = lane & 15, quad = lane >> 4;
  const int m0 = blockIdx.y * 64, n0 = blockIdx.x * 128;
  const int wm = (wave & 1) * 32, wn = (wave >> 1) * 64;

  f32x4 acc[2][4];
#pragma unroll
  for (int i = 0; i < 2; i++)
#pragma unroll
    for (int j = 0; j < 4; j++)
#pragma unroll
      for (int r = 0; r < 4; r++) acc[i][j][r] = 0.f;

  const int nkt = K >> 6;
  for (int kt = 0; kt < nkt; ++kt) {
    __syncthreads();
#pragma unroll
    for (int i = 0; i < 2; ++i) {
      int u = i * 256 + tid;
      int row = u >> 3;
      int kcg = (u & 7) ^ (row & 7);
      g2l16(A + (size_t)(m0 + row) * K + (kt << 6) + (kcg << 3), As + u * 8);
    }
#pragma unroll
    for (int i = 0; i < 4; ++i) {
      int u = i * 256 + tid;
      int row = u >> 3;
      int kcg = (u & 7) ^ (row & 7);
      g2l16(Bt + (size_t)(n0 + row) * K + (kt << 6) + (kcg << 3), Bs + u * 8);
    }
    __syncthreads();
#pragma unroll
    for (int ks = 0; ks < 2; ++ks) {
      const int kc = ks * 4 + quad;
      bf16x8 af[2], bfr[4];
#pragma unroll
      for (int t = 0; t < 2; ++t) {
        int mrow = wm + t * 16 + l15;
        af[t] = *(const bf16x8*)(As + (mrow * 8 + (kc ^ (mrow & 7))) * 8);
      }
#pragma unroll
      for (int t = 0; t < 4; ++t) {
        int nrow = wn + t * 16 + l15;
        bfr[t] = *(const bf16x8*)(Bs + (nrow * 8 + (kc ^ (nrow & 7))) * 8);
      }
#pragma unroll
      for (int mt = 0; mt < 2; ++mt)
#pragma unroll
        for (int nt = 0; nt < 4; ++nt)
          acc[mt][nt] = __builtin_amdgcn_mfma_f32_16x16x32_bf16(af[mt], bfr[nt], acc[mt][nt], 0, 0, 0);
    }
  }
#pragma unroll
  for (int mt = 0; mt < 2; ++mt)
#pragma unroll
    for (int nt = 0; nt < 4; ++nt) {
      int col = n0 + wn + nt * 16 + l15;
      int rowb = m0 + wm + mt * 16 + quad * 4;
      float b = bias[col];
#pragma unroll
      for (int r = 0; r < 4; ++r)
        C[(size_t)(rowb + r) * N + col] = acc[mt][nt][r] + b;
    }
}

// -------- flash attention, key-split x2: fp32 unnormalized partials --------
// grid (bh=32, qb=16, half=2), 4 waves x 32q, 8 key-tiles of 128 per half.
// Fixed-shift base-2 softmax => partials combine by pure addition.
__global__ __launch_bounds__(256, 4) void flash_attn(const unsigned short* __restrict__ QK,
                                                     const unsigned short* __restrict__ Vt,
                                                     float* __restrict__ Oacc,
                                                     float* __restrict__ Lacc) {
  __shared__ alignas(16) unsigned short Ks[128 * 64];   // [key][d], swizzled 16B units
  __shared__ alignas(16) unsigned short Vs[64 * 128];   // [d][key], swizzled 16B units
  const int tid = threadIdx.x, lane = tid & 63, wave = tid >> 6;
  const int l15 = lane & 15, quad = lane >> 4;
  const int bh = blockIdx.x, qb = blockIdx.y, half = blockIdx.z;
  const int b = bh >> 4, h = bh & 15;
  const int q0 = qb * 128 + wave * 32;
  float* Oh = Oacc + (size_t)half * 4096 * 1024;
  float* Lh = Lacc + half * 65536;
  // Q frags (B-operand of S^T): n=l15 -> q, k position = ks*32+quad*8+j
  bf16x8 qf[2][2];
#pragma unroll
  for (int ks = 0; ks < 2; ++ks)
#pragma unroll
    for (int qg = 0; qg < 2; ++qg)
      qf[ks][qg] = *(const bf16x8*)(QK + (size_t)(b * 2048 + q0 + qg * 16 + l15) * 2048 +
                                    h * 64 + ks * 32 + quad * 8);
  f32x4 o[2][4];
#pragma unroll
  for (int qg = 0; qg < 2; qg++)
#pragma unroll
    for (int nt = 0; nt < 4; nt++)
#pragma unroll
      for (int r = 0; r < 4; r++) o[qg][nt][r] = 0.f;
  float li[2] = {0.f, 0.f};
  const f32x4 negb = {-12.f, -12.f, -12.f, -12.f};

  for (int kb = half * 8; kb < half * 8 + 8; ++kb) {
    __syncthreads();
#pragma unroll
    for (int i = 0; i < 4; ++i) {
      int u = i * 256 + tid;
      int krow = u >> 3;
      int kcg = (u & 7) ^ (krow & 7);
      g2l16(QK + (size_t)(b * 2048 + kb * 128 + krow) * 2048 + 1024 + h * 64 + kcg * 8,
            Ks + u * 8);
      int vrow = u >> 4;
      int vcg = (u & 15) ^ (vrow & 7);
      g2l16(Vt + ((size_t)bh * 64 + vrow) * 2048 + kb * 128 + vcg * 8, Vs + u * 8);
    }
    __syncthreads();
    // S^T[key][q] - 12: A=K (m=key), B=Q^T. C-layout: row=key(quad*4+r), col=q(l15)
    f32x4 sacc[2][8];
#pragma unroll
    for (int ks = 0; ks < 2; ++ks) {
      const int kc = ks * 4 + quad;
#pragma unroll
      for (int mt = 0; mt < 8; ++mt) {
        int key = mt * 16 + l15;
        bf16x8 kf = *(const bf16x8*)(Ks + (key * 8 + (kc ^ (key & 7))) * 8);
        if (ks == 0) {
          sacc[0][mt] = __builtin_amdgcn_mfma_f32_16x16x32_bf16(kf, qf[0][0], negb, 0, 0, 0);
          sacc[1][mt] = __builtin_amdgcn_mfma_f32_16x16x32_bf16(kf, qf[0][1], negb, 0, 0, 0);
        } else {
          sacc[0][mt] = __builtin_amdgcn_mfma_f32_16x16x32_bf16(kf, qf[1][0], sacc[0][mt], 0, 0, 0);
          sacc[1][mt] = __builtin_amdgcn_mfma_f32_16x16x32_bf16(kf, qf[1][1], sacc[1][mt], 0, 0, 0);
        }
      }
    }
    // p = exp2(sacc) -> pack in-register as PV B-operand frags
    bf16x4 pf[2][8];
#pragma unroll
    for (int qg = 0; qg < 2; ++qg) {
      float psum = 0.f;
#pragma unroll
      for (int mt = 0; mt < 8; ++mt) {
        float p0 = EXP2(sacc[qg][mt][0]);
        float p1 = EXP2(sacc[qg][mt][1]);
        float p2 = EXP2(sacc[qg][mt][2]);
        float p3 = EXP2(sacc[qg][mt][3]);
        psum += (p0 + p1) + (p2 + p3);
        union { uint2 u; bf16x4 v; } cc;
        cc.u.x = pk_bf16_trunc(p0, p1);
        cc.u.y = pk_bf16_trunc(p2, p3);
        pf[qg][mt] = cc.v;
      }
      li[qg] += psum;
    }
    // O^T += V^T @ P^T: A=V^T (m=d, k=quad*4+j), B=P^T (n=q=l15, k=quad*4+r)
#pragma unroll
    for (int mt = 0; mt < 8; ++mt) {
      const int cu = mt * 2 + (quad >> 1);
#pragma unroll
      for (int nt = 0; nt < 4; ++nt) {
        int dd = nt * 16 + l15;
        bf16x4 vf = *(const bf16x4*)(Vs + (dd * 16 + (cu ^ (dd & 7))) * 8 + (quad & 1) * 4);
        o[0][nt] = mfma16x16x16(vf, pf[0][mt], o[0][nt]);
        o[1][nt] = mfma16x16x16(vf, pf[1][mt], o[1][nt]);
      }
    }
  }
  // epilogue: fp32 partials. O^T layout d = nt*16+quad*4+r, q = qg*16+l15.
#pragma unroll
  for (int qg = 0; qg < 2; ++qg) {
    li[qg] += __shfl_xor(li[qg], 16);
    li[qg] += __shfl_xor(li[qg], 32);
    size_t rowb = (size_t)(b * 2048 + q0 + qg * 16 + l15) * 1024 + h * 64;
#pragma unroll
    for (int nt = 0; nt < 4; ++nt)
      *(f32x4*)(Oh + rowb + nt * 16 + quad * 4) = o[qg][nt];
    if (quad == 0)
      Lh[bh * 2048 + q0 + qg * 16 + l15] = li[qg];
  }
}

// -------- combine halves: A2 = bf16( (O1+O2) * 1.0019 / (l1+l2) ) --------
__global__ __launch_bounds__(256) void combine(const float* __restrict__ Oacc,
                                               const float* __restrict__ Lacc,
                                               unsigned short* __restrict__ A2) {
  int i = blockIdx.x * 256 + threadIdx.x;   // 1,048,576
  f32x4 a = ((const f32x4*)Oacc)[i];
  f32x4 c = ((const f32x4*)(Oacc + 4194304))[i];
  int row = i >> 8;                         // 256 f32x4 per row of 1024
  int col4 = i & 255;
  int t = row & 2047, b = row >> 11, h = col4 >> 4;
  int bh = b * 16 + h;
  float l = Lacc[bh * 2048 + t] + Lacc[65536 + bh * 2048 + t];
  float inv = 1.001953125f / l;             // compensate P truncation bias
  ushort4 o;
  o.x = f2bf((a[0] + c[0]) * inv);
  o.y = f2bf((a[1] + c[1]) * inv);
  o.z = f2bf((a[2] + c[2]) * inv);
  o.w = f2bf((a[3] + c[3]) * inv);
  ((ushort4*)A2)[i] = o;
}

extern "C" void kernel_launch(void* const* d_in, const int* in_sizes, int n_in,
                              void* d_out, int out_size, void* d_ws, size_t ws_size,
                              hipStream_t stream) {
  const float* x    = (const float*)d_in[0];
  const float* Wqkv = (const float*)d_in[1];
  const float* bqkv = (const float*)d_in[2];
  const float* Wout = (const float*)d_in[3];
  const float* bout = (const float*)d_in[4];
  float* out = (float*)d_out;
  char* ws = (char*)d_ws;
  // workspace map (~85 MB)
  float*          COS  = (float*)(ws + 0);                   // 262144
  float*          SIN  = (float*)(ws + 262144);              // 262144
  unsigned short* A1   = (unsigned short*)(ws + 524288);     // 8388608
  unsigned short* W1t  = (unsigned short*)(ws + 8912896);    // 6291456
  unsigned short* W2t  = (unsigned short*)(ws + 15204352);   // 2097152
  unsigned short* QK   = (unsigned short*)(ws + 17301504);   // 16777216  q|k roped (paired layout)
  unsigned short* VT   = (unsigned short*)(ws + 34078720);   // 8388608   v^T [32][64][2048]
  unsigned short* A2   = (unsigned short*)(ws + 42467328);   // 8388608   attn bf16
  float*          OACC = (float*)(ws + 50855936);            // 33554432  2x fp32 partial O
  float*          LACC = (float*)(ws + 84410368);            // 524288    2x fp32 partial l

  prep<<<5376, 256, 0, stream>>>(x, Wqkv, Wout, COS, SIN, A1, W1t, W2t);
  gemm_qkv<<<dim3(24, 32), 256, 0, stream>>>(A1, W1t, bqkv, COS, SIN, QK, VT);
  flash_attn<<<dim3(32, 16, 2), 256, 0, stream>>>(QK, VT, OACC, LACC);
  combine<<<4096, 256, 0, stream>>>(OACC, LACC, A2);
  gemm64<<<dim3(8, 64), 256, 0, stream>>>(A2, W2t, bout, out, 4096, 1024, 1024);
}

// Round 6
// 243.090 us; speedup vs baseline: 1.0718x; 1.0718x over previous
//
#include <hip/hip_runtime.h>

typedef float f32x4 __attribute__((ext_vector_type(4)));
typedef short bf16x8 __attribute__((ext_vector_type(8)));
typedef short bf16x4 __attribute__((ext_vector_type(4)));

#define DEV __device__ __forceinline__

DEV unsigned short f2bf(float x) {
  union { float f; unsigned u; } v; v.f = x;
  unsigned r = v.u + 0x7fffu + ((v.u >> 16) & 1u);
  return (unsigned short)(r >> 16);
}
DEV float bf2f(unsigned short h) {
  union { unsigned u; float f; } v; v.u = ((unsigned)h) << 16;
  return v.f;
}

#if defined(__has_builtin)
# if __has_builtin(__builtin_amdgcn_global_load_lds)
#  define HAVE_GLL 1
# endif
# if __has_builtin(__builtin_amdgcn_exp2f)
#  define EXP2(x) __builtin_amdgcn_exp2f(x)
# else
#  define EXP2(x) exp2f(x)
# endif
#else
# define EXP2(x) exp2f(x)
#endif

// pack trunc-bf16(a) | trunc-bf16(b)<<16 in ONE v_perm_b32
DEV unsigned pk_bf16_trunc(float a, float b) {
  return __builtin_amdgcn_perm(__float_as_uint(b), __float_as_uint(a), 0x07060302u);
}
// rounded pack
DEV unsigned pk_bf16_rnd(float a, float b) {
  return ((unsigned)f2bf(b) << 16) | f2bf(a);
}

// 16B global->LDS. Per-wave: dest = uniform base + lane*16.
DEV void g2l16(const unsigned short* g, unsigned short* l) {
#ifdef HAVE_GLL
  __builtin_amdgcn_global_load_lds((const __attribute__((address_space(1))) void*)g,
                                   (__attribute__((address_space(3))) void*)l, 16, 0, 0);
#else
  *(uint4*)l = *(const uint4*)g;
#endif
}

DEV f32x4 mfma16x16x16(bf16x4 a, bf16x4 b, f32x4 c) {
#if defined(__has_builtin) && __has_builtin(__builtin_amdgcn_mfma_f32_16x16x16bf16_1k)
  return __builtin_amdgcn_mfma_f32_16x16x16bf16_1k(a, b, c, 0, 0, 0);
#else
  asm volatile("v_mfma_f32_16x16x16_bf16 %0, %1, %2, %0" : "+v"(c) : "v"(a), "v"(b));
  return c;
#endif
}

// ======== fused prep: rope table + x cast + both W transposes (one launch) ========
__global__ __launch_bounds__(256) void prep(const float* __restrict__ x,
                                            const float* __restrict__ Wqkv,
                                            const float* __restrict__ Wout,
                                            float* cosb, float* sinb,
                                            unsigned short* __restrict__ A1,
                                            unsigned short* __restrict__ W1t,
                                            unsigned short* __restrict__ W2t) {
  __shared__ float t[64 * 65];
  int blk = blockIdx.x;
  if (blk < 256) {
    int i = blk * 256 + threadIdx.x;
    int tt = i >> 5, d = i & 31;
    float invf = (float)(1.0 / pow(10000.0, (double)d / 32.0));
    float ang = (float)tt * invf;
    cosb[i] = (float)cos((double)ang);
    sinb[i] = (float)sin((double)ang);
    return;
  }
  if (blk < 4352) {
    int i = (blk - 256) * 256 + threadIdx.x;
    f32x4 v = ((const f32x4*)x)[i];
    ushort4 o;
    o.x = f2bf(v[0]); o.y = f2bf(v[1]); o.z = f2bf(v[2]); o.w = f2bf(v[3]);
    ((ushort4*)A1)[i] = o;
    return;
  }
  const float* W; unsigned short* Wt; int N, bidx;
  if (blk < 5120) { W = Wqkv; Wt = W1t; N = 3072; bidx = blk - 4352; }
  else            { W = Wout; Wt = W2t; N = 1024; bidx = blk - 5120; }
  int k0 = (bidx & 15) * 64, n0 = (bidx >> 4) * 64;
  for (int idx = threadIdx.x; idx < 4096; idx += 256) {
    int kl = idx >> 6, nl = idx & 63;
    t[kl * 65 + nl] = W[(size_t)(k0 + kl) * N + n0 + nl];
  }
  __syncthreads();
  for (int idx = threadIdx.x; idx < 4096; idx += 256) {
    int nl = idx >> 6, kl = idx & 63;
    Wt[(size_t)(n0 + nl) * 1024 + k0 + kl] = f2bf(t[kl * 65 + nl]);
  }
}

// ---------------- qkv GEMM + fused RoPE epilogue ----------------
// q/k heads: interleaved rotation pairs (pos 2dr = lo, 2dr+1 = hi); same perm for
// q and k keeps q.k invariant. v: LDS-transposed to [bh][d][t] with 128B row stores.
#define QSCALE 0.180336880f   // 0.125 * log2(e)
__global__ __launch_bounds__(256, 2) void gemm_qkv(
    const unsigned short* __restrict__ A, const unsigned short* __restrict__ Bt,
    const float* __restrict__ bias, const float* __restrict__ cosb,
    const float* __restrict__ sinb, unsigned short* __restrict__ QK,
    unsigned short* __restrict__ Vt) {
  const int K = 1024;
  __shared__ alignas(16) unsigned short SMEM[16384];   // As | Bs ; reused for V transpose
  unsigned short* As = SMEM;           // 128*64
  unsigned short* Bs = SMEM + 8192;    // 128*64
  const int tid = threadIdx.x;
  const int lane = tid & 63, wave = tid >> 6;
  const int l15 = lane & 15, quad = lane >> 4;
  const int m0 = blockIdx.y * 128, n0 = blockIdx.x * 128;
  const int wm = (wave & 1) * 64, wn = (wave >> 1) * 64;

  f32x4 acc[4][4];
#pragma unroll
  for (int i = 0; i < 4; i++)
#pragma unroll
    for (int j = 0; j < 4; j++)
#pragma unroll
      for (int r = 0; r < 4; r++) acc[i][j][r] = 0.f;

  for (int kt = 0; kt < 16; ++kt) {
    __syncthreads();
#pragma unroll
    for (int i = 0; i < 4; ++i) {
      int u = i * 256 + tid;
      int row = u >> 3;
      int kcg = (u & 7) ^ (row & 7);
      g2l16(A  + (size_t)(m0 + row) * K + (kt << 6) + (kcg << 3), As + u * 8);
      g2l16(Bt + (size_t)(n0 + row) * K + (kt << 6) + (kcg << 3), Bs + u * 8);
    }
    __syncthreads();
#pragma unroll
    for (int ks = 0; ks < 2; ++ks) {
      const int kc = ks * 4 + quad;
      bf16x8 af[4], bfr[4];
#pragma unroll
      for (int t = 0; t < 4; ++t) {
        int mrow = wm + t * 16 + l15;
        af[t] = *(const bf16x8*)(As + (mrow * 8 + (kc ^ (mrow & 7))) * 8);
        int nrow = wn + t * 16 + l15;
        bfr[t] = *(const bf16x8*)(Bs + (nrow * 8 + (kc ^ (nrow & 7))) * 8);
      }
#pragma unroll
      for (int mt = 0; mt < 4; ++mt)
#pragma unroll
        for (int nt = 0; nt < 4; ++nt)
          acc[mt][nt] = __builtin_amdgcn_mfma_f32_16x16x32_bf16(af[mt], bfr[nt], acc[mt][nt], 0, 0, 0);
    }
  }
  __syncthreads();                      // all LDS reads done before V-transpose reuse
  // ---- epilogue: C/D layout col=lane&15, row=quad*4+reg ----
  const int headcol = n0 + wn;          // wave-uniform, multiple of 64
  const int b = m0 >> 11;
  float bb[4];
#pragma unroll
  for (int nt = 0; nt < 4; ++nt) bb[nt] = bias[headcol + nt * 16 + l15];

  if (n0 < 2048) {                      // q or k: RoPE in fp32, paired 4B stores
    const float scale = (headcol < 1024) ? QSCALE : 1.f;
#pragma unroll
    for (int mt = 0; mt < 4; ++mt) {
#pragma unroll
      for (int r = 0; r < 4; ++r) {
        int row = m0 + wm + mt * 16 + quad * 4 + r;
        int t = row & 2047;
#pragma unroll
        for (int nt = 0; nt < 2; ++nt) {
          int dr = nt * 16 + l15;       // 0..31
          float c = cosb[t * 32 + dr], s = sinb[t * 32 + dr];
          float v1 = acc[mt][nt][r] + bb[nt];
          float v2 = acc[mt][nt + 2][r] + bb[nt + 2];
          unsigned w = pk_bf16_rnd((v1 * c - v2 * s) * scale, (v2 * c + v1 * s) * scale);
          *(unsigned*)(QK + (size_t)row * 2048 + headcol + 2 * dr) = w;
        }
      }
    }
  } else {                              // v: LDS transpose -> [bh][d][t], 128B row stores
    unsigned short* Tw = SMEM + wave * 4096;   // [d=64][8 units of 8 shorts], col = u^(d&7)
    const int hv = (headcol - 2048) >> 6;
    const int t0 = (m0 + wm) & 2047;
#pragma unroll
    for (int mt = 0; mt < 4; ++mt)
#pragma unroll
      for (int nt = 0; nt < 4; ++nt) {
        int d = nt * 16 + l15;
        uint2 w;
        w.x = pk_bf16_rnd(acc[mt][nt][0] + bb[nt], acc[mt][nt][1] + bb[nt]);
        w.y = pk_bf16_rnd(acc[mt][nt][2] + bb[nt], acc[mt][nt][3] + bb[nt]);
        int u = mt * 2 + (quad >> 1);
        *(uint2*)(Tw + d * 64 + ((u ^ (d & 7)) * 8) + (quad & 1) * 4) = w;
      }
    unsigned short* vbase = Vt + ((size_t)((b * 16 + hv) * 64)) * 2048 + t0;
#pragma unroll
    for (int dp = 0; dp < 8; ++dp) {
      int d = dp * 8 + (lane >> 3);
      int u = lane & 7;
      uint4 w4 = *(uint4*)(Tw + d * 64 + ((u ^ (d & 7)) * 8));
      *(uint4*)(vbase + (size_t)d * 2048 + u * 8) = w4;
    }
  }
}

// ---------------- bf16 GEMM, 64(M)x128(N) tile (out-projection) ----------------
__global__ __launch_bounds__(256, 2) void gemm64(
    const unsigned short* __restrict__ A, const unsigned short* __restrict__ Bt,
    const float* __restrict__ bias, float* __restrict__ C, int M, int N, int K) {
  __shared__ alignas(16) unsigned short As[64 * 64];
  __shared__ alignas(16) unsigned short Bs[128 * 64];
  const int tid = threadIdx.x;
  const int lane = tid & 63, wave = tid >> 6;
  const int l15 = lane & 15, quad = lane >> 4;
  const int m0 = blockIdx.y * 64, n0 = blockIdx.x * 128;
  const int wm = (wave & 1) * 32, wn = (wave >> 1) * 64;

  f32x4 acc[2][4];
#pragma unroll
  for (int i = 0; i < 2; i++)
#pragma unroll
    for (int j = 0; j < 4; j++)
#pragma unroll
      for (int r = 0; r < 4; r++) acc[i][j][r] = 0.f;

  const int nkt = K >> 6;
  for (int kt = 0; kt < nkt; ++kt) {
    __syncthreads();
#pragma unroll
    for (int i = 0; i < 2; ++i) {
      int u = i * 256 + tid;
      int row = u >> 3;
      int kcg = (u & 7) ^ (row & 7);
      g2l16(A + (size_t)(m0 + row) * K + (kt << 6) + (kcg << 3), As + u * 8);
    }
#pragma unroll
    for (int i = 0; i < 4; ++i) {
      int u = i * 256 + tid;
      int row = u >> 3;
      int kcg = (u & 7) ^ (row & 7);
      g2l16(Bt + (size_t)(n0 + row) * K + (kt << 6) + (kcg << 3), Bs + u * 8);
    }
    __syncthreads();
#pragma unroll
    for (int ks = 0; ks < 2; ++ks) {
      const int kc = ks * 4 + quad;
      bf16x8 af[2], bfr[4];
#pragma unroll
      for (int t = 0; t < 2; ++t) {
        int mrow = wm + t * 16 + l15;
        af[t] = *(const bf16x8*)(As + (mrow * 8 + (kc ^ (mrow & 7))) * 8);
      }
#pragma unroll
      for (int t = 0; t < 4; ++t) {
        int nrow = wn + t * 16 + l15;
        bfr[t] = *(const bf16x8*)(Bs + (nrow * 8 + (kc ^ (nrow & 7))) * 8);
      }
#pragma unroll
      for (int mt = 0; mt < 2; ++mt)
#pragma unroll
        for (int nt = 0; nt < 4; ++nt)
          acc[mt][nt] = __builtin_amdgcn_mfma_f32_16x16x32_bf16(af[mt], bfr[nt], acc[mt][nt], 0, 0, 0);
    }
  }
#pragma unroll
  for (int mt = 0; mt < 2; ++mt)
#pragma unroll
    for (int nt = 0; nt < 4; ++nt) {
      int col = n0 + wn + nt * 16 + l15;
      int rowb = m0 + wm + mt * 16 + quad * 4;
      float b = bias[col];
#pragma unroll
      for (int r = 0; r < 4; ++r)
        C[(size_t)(rowb + r) * N + col] = acc[mt][nt][r] + b;
    }
}

// -------- flash attention, key-split x2, lane-linear blob partials --------
// grid (x = bh*2+half [64], y = qb [16]); 4 waves x 32q; 8 key-tiles of 128/half.
// 64 % 8 == 0 => all qb-blocks of one (bh,half) land on one XCD (K/V L2 reuse).
// Fixed-shift base-2 softmax => partials combine by pure addition.
__global__ __launch_bounds__(256, 4) void flash_attn(const unsigned short* __restrict__ QK,
                                                     const unsigned short* __restrict__ Vt,
                                                     float* __restrict__ Oacc,
                                                     float* __restrict__ Lacc) {
  __shared__ alignas(16) unsigned short Ks[128 * 64];   // [key][d], swizzled 16B units
  __shared__ alignas(16) unsigned short Vs[64 * 128];   // [d][key], swizzled 16B units
  const int tid = threadIdx.x, lane = tid & 63, wave = tid >> 6;
  const int l15 = lane & 15, quad = lane >> 4;
  const int bh = blockIdx.x >> 1, half = blockIdx.x & 1, qb = blockIdx.y;
  const int b = bh >> 4, h = bh & 15;
  const int q0 = qb * 128 + wave * 32;
  float* Oh = Oacc + (size_t)half * 4194304;
  float* Lh = Lacc + half * 65536;
  // Q frags (B-operand of S^T): n=l15 -> q, k position = ks*32+quad*8+j
  bf16x8 qf[2][2];
#pragma unroll
  for (int ks = 0; ks < 2; ++ks)
#pragma unroll
    for (int qg = 0; qg < 2; ++qg)
      qf[ks][qg] = *(const bf16x8*)(QK + (size_t)(b * 2048 + q0 + qg * 16 + l15) * 2048 +
                                    h * 64 + ks * 32 + quad * 8);
  f32x4 o[2][4];
#pragma unroll
  for (int qg = 0; qg < 2; qg++)
#pragma unroll
    for (int nt = 0; nt < 4; nt++)
#pragma unroll
      for (int r = 0; r < 4; r++) o[qg][nt][r] = 0.f;
  float li[2] = {0.f, 0.f};
  const f32x4 negb = {-12.f, -12.f, -12.f, -12.f};

  for (int kb = half * 8; kb < half * 8 + 8; ++kb) {
    __syncthreads();
#pragma unroll
    for (int i = 0; i < 4; ++i) {
      int u = i * 256 + tid;
      int krow = u >> 3;
      int kcg = (u & 7) ^ (krow & 7);
      g2l16(QK + (size_t)(b * 2048 + kb * 128 + krow) * 2048 + 1024 + h * 64 + kcg * 8,
            Ks + u * 8);
      int vrow = u >> 4;
      int vcg = (u & 15) ^ (vrow & 7);
      g2l16(Vt + ((size_t)bh * 64 + vrow) * 2048 + kb * 128 + vcg * 8, Vs + u * 8);
    }
    __syncthreads();
    // S^T[key][q] - 12: A=K (m=key), B=Q^T. C-layout: row=key(quad*4+r), col=q(l15)
    f32x4 sacc[2][8];
#pragma unroll
    for (int ks = 0; ks < 2; ++ks) {
      const int kc = ks * 4 + quad;
#pragma unroll
      for (int mt = 0; mt < 8; ++mt) {
        int key = mt * 16 + l15;
        bf16x8 kf = *(const bf16x8*)(Ks + (key * 8 + (kc ^ (key & 7))) * 8);
        if (ks == 0) {
          sacc[0][mt] = __builtin_amdgcn_mfma_f32_16x16x32_bf16(kf, qf[0][0], negb, 0, 0, 0);
          sacc[1][mt] = __builtin_amdgcn_mfma_f32_16x16x32_bf16(kf, qf[0][1], negb, 0, 0, 0);
        } else {
          sacc[0][mt] = __builtin_amdgcn_mfma_f32_16x16x32_bf16(kf, qf[1][0], sacc[0][mt], 0, 0, 0);
          sacc[1][mt] = __builtin_amdgcn_mfma_f32_16x16x32_bf16(kf, qf[1][1], sacc[1][mt], 0, 0, 0);
        }
      }
    }
    // p = exp2(sacc) -> pack in-register as PV B-operand frags
    bf16x4 pf[2][8];
#pragma unroll
    for (int qg = 0; qg < 2; ++qg) {
      float psum = 0.f;
#pragma unroll
      for (int mt = 0; mt < 8; ++mt) {
        float p0 = EXP2(sacc[qg][mt][0]);
        float p1 = EXP2(sacc[qg][mt][1]);
        float p2 = EXP2(sacc[qg][mt][2]);
        float p3 = EXP2(sacc[qg][mt][3]);
        psum += (p0 + p1) + (p2 + p3);
        union { uint2 u; bf16x4 v; } cc;
        cc.u.x = pk_bf16_trunc(p0, p1);
        cc.u.y = pk_bf16_trunc(p2, p3);
        pf[qg][mt] = cc.v;
      }
      li[qg] += psum;
    }
    // O^T += V^T @ P^T: A=V^T (m=d, k=quad*4+j), B=P^T (n=q=l15, k=quad*4+r)
#pragma unroll
    for (int mt = 0; mt < 8; ++mt) {
      const int cu = mt * 2 + (quad >> 1);
#pragma unroll
      for (int nt = 0; nt < 4; ++nt) {
        int dd = nt * 16 + l15;
        bf16x4 vf = *(const bf16x4*)(Vs + (dd * 16 + (cu ^ (dd & 7))) * 8 + (quad & 1) * 4);
        o[0][nt] = mfma16x16x16(vf, pf[0][mt], o[0][nt]);
        o[1][nt] = mfma16x16x16(vf, pf[1][mt], o[1][nt]);
      }
    }
  }
  // epilogue: lane-linear blob per wave (fully coalesced 16B/lane sequential)
  f32x4* Op = (f32x4*)Oh + ((size_t)(bh * 16 + qb) * 4 + wave) * 512;
#pragma unroll
  for (int qg = 0; qg < 2; ++qg) {
    li[qg] += __shfl_xor(li[qg], 16);
    li[qg] += __shfl_xor(li[qg], 32);
#pragma unroll
    for (int nt = 0; nt < 4; ++nt)
      Op[(qg * 4 + nt) * 64 + lane] = o[qg][nt];
    if (quad == 0)
      Lh[(bh * 16 + qb) * 128 + wave * 32 + qg * 16 + l15] = li[qg];
  }
}

// -------- combine halves: LDS transpose, A2 = bf16((O0+O1)*1.0019/(l0+l1)) --------
// grid = 512 blocks (one per (bh,qb) tile), 256 threads.
__global__ __launch_bounds__(256) void combine(const float* __restrict__ Oacc,
                                               const float* __restrict__ Lacc,
                                               unsigned short* __restrict__ A2) {
  __shared__ float T[128 * 64];     // [q][16 units of f32x4], unit col = u ^ (q&15)
  __shared__ float linv[128];
  const int tile = blockIdx.x;      // bh*16 + qb
  const int bh = tile >> 4, qb = tile & 15;
  const int b = bh >> 4, h = bh & 15;
  const int tid = threadIdx.x;
  const f32x4* O0 = (const f32x4*)Oacc + (size_t)tile * 2048;
  const f32x4* O1 = O0 + 1048576;
  if (tid < 128) {
    float l = Lacc[tile * 128 + tid] + Lacc[65536 + tile * 128 + tid];
    linv[tid] = 1.001953125f / l;   // compensate P truncation bias
  }
#pragma unroll
  for (int p = 0; p < 8; ++p) {
    int i = p * 256 + tid;          // 0..2047
    f32x4 s = O0[i] + O1[i];
    int ln = i & 63, nt = (i >> 6) & 3, qg = (i >> 8) & 1, w = i >> 9;
    int q = w * 32 + qg * 16 + (ln & 15);
    int u = nt * 4 + (ln >> 4);     // d unit = d/4
    *(f32x4*)&T[q * 64 + ((u ^ (q & 15)) * 4)] = s;
  }
  __syncthreads();
#pragma unroll
  for (int p = 0; p < 4; ++p) {
    int row = p * 32 + (tid >> 3), ub = (tid & 7) * 2;
    float iv = linv[row];
    f32x4 s0 = *(const f32x4*)&T[row * 64 + ((ub ^ (row & 15)) * 4)];
    f32x4 s1 = *(const f32x4*)&T[row * 64 + (((ub + 1) ^ (row & 15)) * 4)];
    uint4 w4;
    w4.x = pk_bf16_rnd(s0[0] * iv, s0[1] * iv);
    w4.y = pk_bf16_rnd(s0[2] * iv, s0[3] * iv);
    w4.z = pk_bf16_rnd(s1[0] * iv, s1[1] * iv);
    w4.w = pk_bf16_rnd(s1[2] * iv, s1[3] * iv);
    *(uint4*)(A2 + (size_t)(b * 2048 + qb * 128 + row) * 1024 + h * 64 + ub * 4) = w4;
  }
}

extern "C" void kernel_launch(void* const* d_in, const int* in_sizes, int n_in,
                              void* d_out, int out_size, void* d_ws, size_t ws_size,
                              hipStream_t stream) {
  const float* x    = (const float*)d_in[0];
  const float* Wqkv = (const float*)d_in[1];
  const float* bqkv = (const float*)d_in[2];
  const float* Wout = (const float*)d_in[3];
  const float* bout = (const float*)d_in[4];
  float* out = (float*)d_out;
  char* ws = (char*)d_ws;
  // workspace map (~85 MB)
  float*          COS  = (float*)(ws + 0);                   // 262144
  float*          SIN  = (float*)(ws + 262144);              // 262144
  unsigned short* A1   = (unsigned short*)(ws + 524288);     // 8388608
  unsigned short* W1t  = (unsigned short*)(ws + 8912896);    // 6291456
  unsigned short* W2t  = (unsigned short*)(ws + 15204352);   // 2097152
  unsigned short* QK   = (unsigned short*)(ws + 17301504);   // 16777216  q|k roped (paired layout)
  unsigned short* VT   = (unsigned short*)(ws + 34078720);   // 8388608   v^T [32][64][2048]
  unsigned short* A2   = (unsigned short*)(ws + 42467328);   // 8388608   attn bf16
  float*          OACC = (float*)(ws + 50855936);            // 33554432  2x fp32 partial O (blobs)
  float*          LACC = (float*)(ws + 84410368);            // 524288    2x fp32 partial l

  prep<<<5376, 256, 0, stream>>>(x, Wqkv, Wout, COS, SIN, A1, W1t, W2t);
  gemm_qkv<<<dim3(24, 32), 256, 0, stream>>>(A1, W1t, bqkv, COS, SIN, QK, VT);
  flash_attn<<<dim3(64, 16), 256, 0, stream>>>(QK, VT, OACC, LACC);
  combine<<<512, 256, 0, stream>>>(OACC, LACC, A2);
  gemm64<<<dim3(8, 64), 256, 0, stream>>>(A2, W2t, bout, out, 4096, 1024, 1024);
}

// Round 7
// 192.685 us; speedup vs baseline: 1.3522x; 1.2616x over previous
//
#include <hip/hip_runtime.h>

typedef float f32x4 __attribute__((ext_vector_type(4)));
typedef short bf16x8 __attribute__((ext_vector_type(8)));
typedef short bf16x4 __attribute__((ext_vector_type(4)));

#define DEV __device__ __forceinline__

DEV unsigned short f2bf(float x) {
  union { float f; unsigned u; } v; v.f = x;
  unsigned r = v.u + 0x7fffu + ((v.u >> 16) & 1u);
  return (unsigned short)(r >> 16);
}
DEV float bf2f(unsigned short h) {
  union { unsigned u; float f; } v; v.u = ((unsigned)h) << 16;
  return v.f;
}

#if defined(__has_builtin)
# if __has_builtin(__builtin_amdgcn_global_load_lds)
#  define HAVE_GLL 1
# endif
# if __has_builtin(__builtin_amdgcn_exp2f)
#  define EXP2(x) __builtin_amdgcn_exp2f(x)
# else
#  define EXP2(x) exp2f(x)
# endif
#else
# define EXP2(x) exp2f(x)
#endif

// pack trunc-bf16(a) | trunc-bf16(b)<<16 in ONE v_perm_b32
DEV unsigned pk_bf16_trunc(float a, float b) {
  return __builtin_amdgcn_perm(__float_as_uint(b), __float_as_uint(a), 0x07060302u);
}
// rounded pack
DEV unsigned pk_bf16_rnd(float a, float b) {
  return ((unsigned)f2bf(b) << 16) | f2bf(a);
}

// 16B global->LDS. Per-wave: dest = uniform base + lane*16.
DEV void g2l16(const unsigned short* g, unsigned short* l) {
#ifdef HAVE_GLL
  __builtin_amdgcn_global_load_lds((const __attribute__((address_space(1))) void*)g,
                                   (__attribute__((address_space(3))) void*)l, 16, 0, 0);
#else
  *(uint4*)l = *(const uint4*)g;
#endif
}

DEV f32x4 mfma16x16x16(bf16x4 a, bf16x4 b, f32x4 c) {
#if defined(__has_builtin) && __has_builtin(__builtin_amdgcn_mfma_f32_16x16x16bf16_1k)
  return __builtin_amdgcn_mfma_f32_16x16x16bf16_1k(a, b, c, 0, 0, 0);
#else
  asm volatile("v_mfma_f32_16x16x16_bf16 %0, %1, %2, %0" : "+v"(c) : "v"(a), "v"(b));
  return c;
#endif
}

// ======== fused prep: rope table + x cast + both W transposes (one launch) ========
__global__ __launch_bounds__(256) void prep(const float* __restrict__ x,
                                            const float* __restrict__ Wqkv,
                                            const float* __restrict__ Wout,
                                            float* cosb, float* sinb,
                                            unsigned short* __restrict__ A1,
                                            unsigned short* __restrict__ W1t,
                                            unsigned short* __restrict__ W2t) {
  __shared__ float t[64 * 65];
  int blk = blockIdx.x;
  if (blk < 256) {
    int i = blk * 256 + threadIdx.x;
    int tt = i >> 5, d = i & 31;
    float invf = (float)(1.0 / pow(10000.0, (double)d / 32.0));
    float ang = (float)tt * invf;
    cosb[i] = (float)cos((double)ang);
    sinb[i] = (float)sin((double)ang);
    return;
  }
  if (blk < 4352) {
    int i = (blk - 256) * 256 + threadIdx.x;
    f32x4 v = ((const f32x4*)x)[i];
    ushort4 o;
    o.x = f2bf(v[0]); o.y = f2bf(v[1]); o.z = f2bf(v[2]); o.w = f2bf(v[3]);
    ((ushort4*)A1)[i] = o;
    return;
  }
  const float* W; unsigned short* Wt; int N, bidx;
  if (blk < 5120) { W = Wqkv; Wt = W1t; N = 3072; bidx = blk - 4352; }
  else            { W = Wout; Wt = W2t; N = 1024; bidx = blk - 5120; }
  int k0 = (bidx & 15) * 64, n0 = (bidx >> 4) * 64;
  for (int idx = threadIdx.x; idx < 4096; idx += 256) {
    int kl = idx >> 6, nl = idx & 63;
    t[kl * 65 + nl] = W[(size_t)(k0 + kl) * N + n0 + nl];
  }
  __syncthreads();
  for (int idx = threadIdx.x; idx < 4096; idx += 256) {
    int nl = idx >> 6, kl = idx & 63;
    Wt[(size_t)(n0 + nl) * 1024 + k0 + kl] = f2bf(t[kl * 65 + nl]);
  }
}

// ---------------- qkv GEMM + fused RoPE epilogue ----------------
// q/k heads: interleaved rotation pairs (pos 2dr = lo, 2dr+1 = hi); same perm for
// q and k keeps q.k invariant. v: LDS-transposed to [bh][d][t] with 128B row stores.
#define QSCALE 0.180336880f   // 0.125 * log2(e)
__global__ __launch_bounds__(256, 2) void gemm_qkv(
    const unsigned short* __restrict__ A, const unsigned short* __restrict__ Bt,
    const float* __restrict__ bias, const float* __restrict__ cosb,
    const float* __restrict__ sinb, unsigned short* __restrict__ QK,
    unsigned short* __restrict__ Vt) {
  const int K = 1024;
  __shared__ alignas(16) unsigned short SMEM[16384];   // As | Bs ; reused for V transpose
  unsigned short* As = SMEM;           // 128*64
  unsigned short* Bs = SMEM + 8192;    // 128*64
  const int tid = threadIdx.x;
  const int lane = tid & 63, wave = tid >> 6;
  const int l15 = lane & 15, quad = lane >> 4;
  const int m0 = blockIdx.y * 128, n0 = blockIdx.x * 128;
  const int wm = (wave & 1) * 64, wn = (wave >> 1) * 64;

  f32x4 acc[4][4];
#pragma unroll
  for (int i = 0; i < 4; i++)
#pragma unroll
    for (int j = 0; j < 4; j++)
#pragma unroll
      for (int r = 0; r < 4; r++) acc[i][j][r] = 0.f;

  for (int kt = 0; kt < 16; ++kt) {
    __syncthreads();
#pragma unroll
    for (int i = 0; i < 4; ++i) {
      int u = i * 256 + tid;
      int row = u >> 3;
      int kcg = (u & 7) ^ (row & 7);
      g2l16(A  + (size_t)(m0 + row) * K + (kt << 6) + (kcg << 3), As + u * 8);
      g2l16(Bt + (size_t)(n0 + row) * K + (kt << 6) + (kcg << 3), Bs + u * 8);
    }
    __syncthreads();
#pragma unroll
    for (int ks = 0; ks < 2; ++ks) {
      const int kc = ks * 4 + quad;
      bf16x8 af[4], bfr[4];
#pragma unroll
      for (int t = 0; t < 4; ++t) {
        int mrow = wm + t * 16 + l15;
        af[t] = *(const bf16x8*)(As + (mrow * 8 + (kc ^ (mrow & 7))) * 8);
        int nrow = wn + t * 16 + l15;
        bfr[t] = *(const bf16x8*)(Bs + (nrow * 8 + (kc ^ (nrow & 7))) * 8);
      }
#pragma unroll
      for (int mt = 0; mt < 4; ++mt)
#pragma unroll
        for (int nt = 0; nt < 4; ++nt)
          acc[mt][nt] = __builtin_amdgcn_mfma_f32_16x16x32_bf16(af[mt], bfr[nt], acc[mt][nt], 0, 0, 0);
    }
  }
  __syncthreads();                      // all LDS reads done before V-transpose reuse
  // ---- epilogue: C/D layout col=lane&15, row=quad*4+reg ----
  const int headcol = n0 + wn;          // wave-uniform, multiple of 64
  const int b = m0 >> 11;
  float bb[4];
#pragma unroll
  for (int nt = 0; nt < 4; ++nt) bb[nt] = bias[headcol + nt * 16 + l15];

  if (n0 < 2048) {                      // q or k: RoPE in fp32, paired 4B stores
    const float scale = (headcol < 1024) ? QSCALE : 1.f;
#pragma unroll
    for (int mt = 0; mt < 4; ++mt) {
#pragma unroll
      for (int r = 0; r < 4; ++r) {
        int row = m0 + wm + mt * 16 + quad * 4 + r;
        int t = row & 2047;
#pragma unroll
        for (int nt = 0; nt < 2; ++nt) {
          int dr = nt * 16 + l15;       // 0..31
          float c = cosb[t * 32 + dr], s = sinb[t * 32 + dr];
          float v1 = acc[mt][nt][r] + bb[nt];
          float v2 = acc[mt][nt + 2][r] + bb[nt + 2];
          unsigned w = pk_bf16_rnd((v1 * c - v2 * s) * scale, (v2 * c + v1 * s) * scale);
          *(unsigned*)(QK + (size_t)row * 2048 + headcol + 2 * dr) = w;
        }
      }
    }
  } else {                              // v: LDS transpose -> [bh][d][t], 128B row stores
    unsigned short* Tw = SMEM + wave * 4096;   // [d=64][8 units of 8 shorts], col = u^(d&7)
    const int hv = (headcol - 2048) >> 6;
    const int t0 = (m0 + wm) & 2047;
#pragma unroll
    for (int mt = 0; mt < 4; ++mt)
#pragma unroll
      for (int nt = 0; nt < 4; ++nt) {
        int d = nt * 16 + l15;
        uint2 w;
        w.x = pk_bf16_rnd(acc[mt][nt][0] + bb[nt], acc[mt][nt][1] + bb[nt]);
        w.y = pk_bf16_rnd(acc[mt][nt][2] + bb[nt], acc[mt][nt][3] + bb[nt]);
        int u = mt * 2 + (quad >> 1);
        *(uint2*)(Tw + d * 64 + ((u ^ (d & 7)) * 8) + (quad & 1) * 4) = w;
      }
    unsigned short* vbase = Vt + ((size_t)((b * 16 + hv) * 64)) * 2048 + t0;
#pragma unroll
    for (int dp = 0; dp < 8; ++dp) {
      int d = dp * 8 + (lane >> 3);
      int u = lane & 7;
      uint4 w4 = *(uint4*)(Tw + d * 64 + ((u ^ (d & 7)) * 8));
      *(uint4*)(vbase + (size_t)d * 2048 + u * 8) = w4;
    }
  }
}

// ---------------- bf16 GEMM, 64(M)x128(N) tile (out-projection) ----------------
__global__ __launch_bounds__(256, 2) void gemm64(
    const unsigned short* __restrict__ A, const unsigned short* __restrict__ Bt,
    const float* __restrict__ bias, float* __restrict__ C, int M, int N, int K) {
  __shared__ alignas(16) unsigned short As[64 * 64];
  __shared__ alignas(16) unsigned short Bs[128 * 64];
  const int tid = threadIdx.x;
  const int lane = tid & 63, wave = tid >> 6;
  const int l15 = lane & 15, quad = lane >> 4;
  const int m0 = blockIdx.y * 64, n0 = blockIdx.x * 128;
  const int wm = (wave & 1) * 32, wn = (wave >> 1) * 64;

  f32x4 acc[2][4];
#pragma unroll
  for (int i = 0; i < 2; i++)
#pragma unroll
    for (int j = 0; j < 4; j++)
#pragma unroll
      for (int r = 0; r < 4; r++) acc[i][j][r] = 0.f;

  const int nkt = K >> 6;
  for (int kt = 0; kt < nkt; ++kt) {
    __syncthreads();
#pragma unroll
    for (int i = 0; i < 2; ++i) {
      int u = i * 256 + tid;
      int row = u >> 3;
      int kcg = (u & 7) ^ (row & 7);
      g2l16(A + (size_t)(m0 + row) * K + (kt << 6) + (kcg << 3), As + u * 8);
    }
#pragma unroll
    for (int i = 0; i < 4; ++i) {
      int u = i * 256 + tid;
      int row = u >> 3;
      int kcg = (u & 7) ^ (row & 7);
      g2l16(Bt + (size_t)(n0 + row) * K + (kt << 6) + (kcg << 3), Bs + u * 8);
    }
    __syncthreads();
#pragma unroll
    for (int ks = 0; ks < 2; ++ks) {
      const int kc = ks * 4 + quad;
      bf16x8 af[2], bfr[4];
#pragma unroll
      for (int t = 0; t < 2; ++t) {
        int mrow = wm + t * 16 + l15;
        af[t] = *(const bf16x8*)(As + (mrow * 8 + (kc ^ (mrow & 7))) * 8);
      }
#pragma unroll
      for (int t = 0; t < 4; ++t) {
        int nrow = wn + t * 16 + l15;
        bfr[t] = *(const bf16x8*)(Bs + (nrow * 8 + (kc ^ (nrow & 7))) * 8);
      }
#pragma unroll
      for (int mt = 0; mt < 2; ++mt)
#pragma unroll
        for (int nt = 0; nt < 4; ++nt)
          acc[mt][nt] = __builtin_amdgcn_mfma_f32_16x16x32_bf16(af[mt], bfr[nt], acc[mt][nt], 0, 0, 0);
    }
  }
#pragma unroll
  for (int mt = 0; mt < 2; ++mt)
#pragma unroll
    for (int nt = 0; nt < 4; ++nt) {
      int col = n0 + wn + nt * 16 + l15;
      int rowb = m0 + wm + mt * 16 + quad * 4;
      float b = bias[col];
#pragma unroll
      for (int r = 0; r < 4; ++r)
        C[(size_t)(rowb + r) * N + col] = acc[mt][nt][r] + b;
    }
}

// -------- flash attention, key-split x2, lane-linear blob partials --------
// grid (x = bh*2+half [64], y = qb [16]); 4 waves x 32q; 8 key-tiles of 128/half.
// launch_bounds (256,2): VGPR=104 codegen (NO SPILLS — the (256,4) variant forced
// VGPR=64 and spilled ~350MB/dispatch to scratch, R5/R6 regression). Real occupancy
// is still 4 blocks/CU from resources (104 VGPR -> 4 waves/SIMD, 32KB LDS -> 5).
__global__ __launch_bounds__(256, 2) void flash_attn(const unsigned short* __restrict__ QK,
                                                     const unsigned short* __restrict__ Vt,
                                                     float* __restrict__ Oacc,
                                                     float* __restrict__ Lacc) {
  __shared__ alignas(16) unsigned short Ks[128 * 64];   // [key][d], swizzled 16B units
  __shared__ alignas(16) unsigned short Vs[64 * 128];   // [d][key], swizzled 16B units
  const int tid = threadIdx.x, lane = tid & 63, wave = tid >> 6;
  const int l15 = lane & 15, quad = lane >> 4;
  const int bh = blockIdx.x >> 1, half = blockIdx.x & 1, qb = blockIdx.y;
  const int b = bh >> 4, h = bh & 15;
  const int q0 = qb * 128 + wave * 32;
  float* Oh = Oacc + (size_t)half * 4194304;
  float* Lh = Lacc + half * 65536;
  // Q frags (B-operand of S^T): n=l15 -> q, k position = ks*32+quad*8+j
  bf16x8 qf[2][2];
#pragma unroll
  for (int ks = 0; ks < 2; ++ks)
#pragma unroll
    for (int qg = 0; qg < 2; ++qg)
      qf[ks][qg] = *(const bf16x8*)(QK + (size_t)(b * 2048 + q0 + qg * 16 + l15) * 2048 +
                                    h * 64 + ks * 32 + quad * 8);
  f32x4 o[2][4];
#pragma unroll
  for (int qg = 0; qg < 2; qg++)
#pragma unroll
    for (int nt = 0; nt < 4; nt++)
#pragma unroll
      for (int r = 0; r < 4; r++) o[qg][nt][r] = 0.f;
  float li[2] = {0.f, 0.f};
  const f32x4 negb = {-12.f, -12.f, -12.f, -12.f};

  for (int kb = half * 8; kb < half * 8 + 8; ++kb) {
    __syncthreads();
#pragma unroll
    for (int i = 0; i < 4; ++i) {
      int u = i * 256 + tid;
      int krow = u >> 3;
      int kcg = (u & 7) ^ (krow & 7);
      g2l16(QK + (size_t)(b * 2048 + kb * 128 + krow) * 2048 + 1024 + h * 64 + kcg * 8,
            Ks + u * 8);
      int vrow = u >> 4;
      int vcg = (u & 15) ^ (vrow & 7);
      g2l16(Vt + ((size_t)bh * 64 + vrow) * 2048 + kb * 128 + vcg * 8, Vs + u * 8);
    }
    __syncthreads();
    // S^T[key][q] - 12: A=K (m=key), B=Q^T. C-layout: row=key(quad*4+r), col=q(l15)
    f32x4 sacc[2][8];
#pragma unroll
    for (int ks = 0; ks < 2; ++ks) {
      const int kc = ks * 4 + quad;
#pragma unroll
      for (int mt = 0; mt < 8; ++mt) {
        int key = mt * 16 + l15;
        bf16x8 kf = *(const bf16x8*)(Ks + (key * 8 + (kc ^ (key & 7))) * 8);
        if (ks == 0) {
          sacc[0][mt] = __builtin_amdgcn_mfma_f32_16x16x32_bf16(kf, qf[0][0], negb, 0, 0, 0);
          sacc[1][mt] = __builtin_amdgcn_mfma_f32_16x16x32_bf16(kf, qf[0][1], negb, 0, 0, 0);
        } else {
          sacc[0][mt] = __builtin_amdgcn_mfma_f32_16x16x32_bf16(kf, qf[1][0], sacc[0][mt], 0, 0, 0);
          sacc[1][mt] = __builtin_amdgcn_mfma_f32_16x16x32_bf16(kf, qf[1][1], sacc[1][mt], 0, 0, 0);
        }
      }
    }
    // p = exp2(sacc) -> pack in-register as PV B-operand frags
    bf16x4 pf[2][8];
#pragma unroll
    for (int qg = 0; qg < 2; ++qg) {
      float psum = 0.f;
#pragma unroll
      for (int mt = 0; mt < 8; ++mt) {
        float p0 = EXP2(sacc[qg][mt][0]);
        float p1 = EXP2(sacc[qg][mt][1]);
        float p2 = EXP2(sacc[qg][mt][2]);
        float p3 = EXP2(sacc[qg][mt][3]);
        psum += (p0 + p1) + (p2 + p3);
        union { uint2 u; bf16x4 v; } cc;
        cc.u.x = pk_bf16_trunc(p0, p1);
        cc.u.y = pk_bf16_trunc(p2, p3);
        pf[qg][mt] = cc.v;
      }
      li[qg] += psum;
    }
    // O^T += V^T @ P^T: A=V^T (m=d, k=quad*4+j), B=P^T (n=q=l15, k=quad*4+r)
#pragma unroll
    for (int mt = 0; mt < 8; ++mt) {
      const int cu = mt * 2 + (quad >> 1);
#pragma unroll
      for (int nt = 0; nt < 4; ++nt) {
        int dd = nt * 16 + l15;
        bf16x4 vf = *(const bf16x4*)(Vs + (dd * 16 + (cu ^ (dd & 7))) * 8 + (quad & 1) * 4);
        o[0][nt] = mfma16x16x16(vf, pf[0][mt], o[0][nt]);
        o[1][nt] = mfma16x16x16(vf, pf[1][mt], o[1][nt]);
      }
    }
  }
  // epilogue: lane-linear blob per wave (fully coalesced 16B/lane sequential)
  f32x4* Op = (f32x4*)Oh + ((size_t)(bh * 16 + qb) * 4 + wave) * 512;
#pragma unroll
  for (int qg = 0; qg < 2; ++qg) {
    li[qg] += __shfl_xor(li[qg], 16);
    li[qg] += __shfl_xor(li[qg], 32);
#pragma unroll
    for (int nt = 0; nt < 4; ++nt)
      Op[(qg * 4 + nt) * 64 + lane] = o[qg][nt];
    if (quad == 0)
      Lh[(bh * 16 + qb) * 128 + wave * 32 + qg * 16 + l15] = li[qg];
  }
}

// -------- combine halves: LDS transpose, A2 = bf16((O0+O1)*1.0019/(l0+l1)) --------
// grid = 512 blocks (one per (bh,qb) tile), 256 threads.
__global__ __launch_bounds__(256) void combine(const float* __restrict__ Oacc,
                                               const float* __restrict__ Lacc,
                                               unsigned short* __restrict__ A2) {
  __shared__ float T[128 * 64];     // [q][16 units of f32x4], unit col = u ^ (q&15)
  __shared__ float linv[128];
  const int tile = blockIdx.x;      // bh*16 + qb
  const int bh = tile >> 4, qb = tile & 15;
  const int b = bh >> 4, h = bh & 15;
  const int tid = threadIdx.x;
  const f32x4* O0 = (const f32x4*)Oacc + (size_t)tile * 2048;
  const f32x4* O1 = O0 + 1048576;
  if (tid < 128) {
    float l = Lacc[tile * 128 + tid] + Lacc[65536 + tile * 128 + tid];
    linv[tid] = 1.001953125f / l;   // compensate P truncation bias
  }
#pragma unroll
  for (int p = 0; p < 8; ++p) {
    int i = p * 256 + tid;          // 0..2047
    f32x4 s = O0[i] + O1[i];
    int ln = i & 63, nt = (i >> 6) & 3, qg = (i >> 8) & 1, w = i >> 9;
    int q = w * 32 + qg * 16 + (ln & 15);
    int u = nt * 4 + (ln >> 4);     // d unit = d/4
    *(f32x4*)&T[q * 64 + ((u ^ (q & 15)) * 4)] = s;
  }
  __syncthreads();
#pragma unroll
  for (int p = 0; p < 4; ++p) {
    int row = p * 32 + (tid >> 3), ub = (tid & 7) * 2;
    float iv = linv[row];
    f32x4 s0 = *(const f32x4*)&T[row * 64 + ((ub ^ (row & 15)) * 4)];
    f32x4 s1 = *(const f32x4*)&T[row * 64 + (((ub + 1) ^ (row & 15)) * 4)];
    uint4 w4;
    w4.x = pk_bf16_rnd(s0[0] * iv, s0[1] * iv);
    w4.y = pk_bf16_rnd(s0[2] * iv, s0[3] * iv);
    w4.z = pk_bf16_rnd(s1[0] * iv, s1[1] * iv);
    w4.w = pk_bf16_rnd(s1[2] * iv, s1[3] * iv);
    *(uint4*)(A2 + (size_t)(b * 2048 + qb * 128 + row) * 1024 + h * 64 + ub * 4) = w4;
  }
}

extern "C" void kernel_launch(void* const* d_in, const int* in_sizes, int n_in,
                              void* d_out, int out_size, void* d_ws, size_t ws_size,
                              hipStream_t stream) {
  const float* x    = (const float*)d_in[0];
  const float* Wqkv = (const float*)d_in[1];
  const float* bqkv = (const float*)d_in[2];
  const float* Wout = (const float*)d_in[3];
  const float* bout = (const float*)d_in[4];
  float* out = (float*)d_out;
  char* ws = (char*)d_ws;
  // workspace map (~85 MB)
  float*          COS  = (float*)(ws + 0);                   // 262144
  float*          SIN  = (float*)(ws + 262144);              // 262144
  unsigned short* A1   = (unsigned short*)(ws + 524288);     // 8388608
  unsigned short* W1t  = (unsigned short*)(ws + 8912896);    // 6291456
  unsigned short* W2t  = (unsigned short*)(ws + 15204352);   // 2097152
  unsigned short* QK   = (unsigned short*)(ws + 17301504);   // 16777216  q|k roped (paired layout)
  unsigned short* VT   = (unsigned short*)(ws + 34078720);   // 8388608   v^T [32][64][2048]
  unsigned short* A2   = (unsigned short*)(ws + 42467328);   // 8388608   attn bf16
  float*          OACC = (float*)(ws + 50855936);            // 33554432  2x fp32 partial O (blobs)
  float*          LACC = (float*)(ws + 84410368);            // 524288    2x fp32 partial l

  prep<<<5376, 256, 0, stream>>>(x, Wqkv, Wout, COS, SIN, A1, W1t, W2t);
  gemm_qkv<<<dim3(24, 32), 256, 0, stream>>>(A1, W1t, bqkv, COS, SIN, QK, VT);
  flash_attn<<<dim3(64, 16), 256, 0, stream>>>(QK, VT, OACC, LACC);
  combine<<<512, 256, 0, stream>>>(OACC, LACC, A2);
  gemm64<<<dim3(8, 64), 256, 0, stream>>>(A2, W2t, bout, out, 4096, 1024, 1024);
}

// Round 8
// 190.229 us; speedup vs baseline: 1.3696x; 1.0129x over previous
//
#include <hip/hip_runtime.h>

typedef float f32x4 __attribute__((ext_vector_type(4)));
typedef short bf16x8 __attribute__((ext_vector_type(8)));

#define DEV __device__ __forceinline__

DEV unsigned short f2bf(float x) {
  union { float f; unsigned u; } v; v.f = x;
  unsigned r = v.u + 0x7fffu + ((v.u >> 16) & 1u);
  return (unsigned short)(r >> 16);
}
DEV float bf2f(unsigned short h) {
  union { unsigned u; float f; } v; v.u = ((unsigned)h) << 16;
  return v.f;
}

#if defined(__has_builtin)
# if __has_builtin(__builtin_amdgcn_global_load_lds)
#  define HAVE_GLL 1
# endif
# if __has_builtin(__builtin_amdgcn_exp2f)
#  define EXP2(x) __builtin_amdgcn_exp2f(x)
# else
#  define EXP2(x) exp2f(x)
# endif
#else
# define EXP2(x) exp2f(x)
#endif

// pack trunc-bf16(a) | trunc-bf16(b)<<16 in ONE v_perm_b32
DEV unsigned pk_bf16_trunc(float a, float b) {
  return __builtin_amdgcn_perm(__float_as_uint(b), __float_as_uint(a), 0x07060302u);
}
// rounded pack
DEV unsigned pk_bf16_rnd(float a, float b) {
  return ((unsigned)f2bf(b) << 16) | f2bf(a);
}

// 16B global->LDS. Per-wave: dest = uniform base + lane*16.
DEV void g2l16(const unsigned short* g, unsigned short* l) {
#ifdef HAVE_GLL
  __builtin_amdgcn_global_load_lds((const __attribute__((address_space(1))) void*)g,
                                   (__attribute__((address_space(3))) void*)l, 16, 0, 0);
#else
  *(uint4*)l = *(const uint4*)g;
#endif
}

// ======== fused prep: rope table + x cast + both W transposes (one launch) ========
__global__ __launch_bounds__(256) void prep(const float* __restrict__ x,
                                            const float* __restrict__ Wqkv,
                                            const float* __restrict__ Wout,
                                            float* cosb, float* sinb,
                                            unsigned short* __restrict__ A1,
                                            unsigned short* __restrict__ W1t,
                                            unsigned short* __restrict__ W2t) {
  __shared__ float t[64 * 65];
  int blk = blockIdx.x;
  if (blk < 256) {
    int i = blk * 256 + threadIdx.x;
    int tt = i >> 5, d = i & 31;
    float invf = (float)(1.0 / pow(10000.0, (double)d / 32.0));
    float ang = (float)tt * invf;
    cosb[i] = (float)cos((double)ang);
    sinb[i] = (float)sin((double)ang);
    return;
  }
  if (blk < 4352) {
    int i = (blk - 256) * 256 + threadIdx.x;
    f32x4 v = ((const f32x4*)x)[i];
    ushort4 o;
    o.x = f2bf(v[0]); o.y = f2bf(v[1]); o.z = f2bf(v[2]); o.w = f2bf(v[3]);
    ((ushort4*)A1)[i] = o;
    return;
  }
  const float* W; unsigned short* Wt; int N, bidx;
  if (blk < 5120) { W = Wqkv; Wt = W1t; N = 3072; bidx = blk - 4352; }
  else            { W = Wout; Wt = W2t; N = 1024; bidx = blk - 5120; }
  int k0 = (bidx & 15) * 64, n0 = (bidx >> 4) * 64;
  for (int idx = threadIdx.x; idx < 4096; idx += 256) {
    int kl = idx >> 6, nl = idx & 63;
    t[kl * 65 + nl] = W[(size_t)(k0 + kl) * N + n0 + nl];
  }
  __syncthreads();
  for (int idx = threadIdx.x; idx < 4096; idx += 256) {
    int nl = idx >> 6, kl = idx & 63;
    Wt[(size_t)(n0 + nl) * 1024 + k0 + kl] = f2bf(t[kl * 65 + nl]);
  }
}

// ---------------- qkv GEMM + fused RoPE epilogue ----------------
// q/k heads: interleaved rotation pairs (pos 2dr = lo, 2dr+1 = hi); same perm for
// q and k keeps q.k invariant. v: LDS-transposed to [bh][d][t] with 128B row stores.
#define QSCALE 0.180336880f   // 0.125 * log2(e)
__global__ __launch_bounds__(256, 2) void gemm_qkv(
    const unsigned short* __restrict__ A, const unsigned short* __restrict__ Bt,
    const float* __restrict__ bias, const float* __restrict__ cosb,
    const float* __restrict__ sinb, unsigned short* __restrict__ QK,
    unsigned short* __restrict__ Vt) {
  const int K = 1024;
  __shared__ alignas(16) unsigned short SMEM[16384];   // As | Bs ; reused for V transpose
  unsigned short* As = SMEM;           // 128*64
  unsigned short* Bs = SMEM + 8192;    // 128*64
  const int tid = threadIdx.x;
  const int lane = tid & 63, wave = tid >> 6;
  const int l15 = lane & 15, quad = lane >> 4;
  const int m0 = blockIdx.y * 128, n0 = blockIdx.x * 128;
  const int wm = (wave & 1) * 64, wn = (wave >> 1) * 64;

  f32x4 acc[4][4];
#pragma unroll
  for (int i = 0; i < 4; i++)
#pragma unroll
    for (int j = 0; j < 4; j++)
#pragma unroll
      for (int r = 0; r < 4; r++) acc[i][j][r] = 0.f;

  for (int kt = 0; kt < 16; ++kt) {
    __syncthreads();
#pragma unroll
    for (int i = 0; i < 4; ++i) {
      int u = i * 256 + tid;
      int row = u >> 3;
      int kcg = (u & 7) ^ (row & 7);
      g2l16(A  + (size_t)(m0 + row) * K + (kt << 6) + (kcg << 3), As + u * 8);
      g2l16(Bt + (size_t)(n0 + row) * K + (kt << 6) + (kcg << 3), Bs + u * 8);
    }
    __syncthreads();
#pragma unroll
    for (int ks = 0; ks < 2; ++ks) {
      const int kc = ks * 4 + quad;
      bf16x8 af[4], bfr[4];
#pragma unroll
      for (int t = 0; t < 4; ++t) {
        int mrow = wm + t * 16 + l15;
        af[t] = *(const bf16x8*)(As + (mrow * 8 + (kc ^ (mrow & 7))) * 8);
        int nrow = wn + t * 16 + l15;
        bfr[t] = *(const bf16x8*)(Bs + (nrow * 8 + (kc ^ (nrow & 7))) * 8);
      }
#pragma unroll
      for (int mt = 0; mt < 4; ++mt)
#pragma unroll
        for (int nt = 0; nt < 4; ++nt)
          acc[mt][nt] = __builtin_amdgcn_mfma_f32_16x16x32_bf16(af[mt], bfr[nt], acc[mt][nt], 0, 0, 0);
    }
  }
  __syncthreads();                      // all LDS reads done before V-transpose reuse
  // ---- epilogue: C/D layout col=lane&15, row=quad*4+reg ----
  const int headcol = n0 + wn;          // wave-uniform, multiple of 64
  const int b = m0 >> 11;
  float bb[4];
#pragma unroll
  for (int nt = 0; nt < 4; ++nt) bb[nt] = bias[headcol + nt * 16 + l15];

  if (n0 < 2048) {                      // q or k: RoPE in fp32, paired 4B stores
    const float scale = (headcol < 1024) ? QSCALE : 1.f;
#pragma unroll
    for (int mt = 0; mt < 4; ++mt) {
#pragma unroll
      for (int r = 0; r < 4; ++r) {
        int row = m0 + wm + mt * 16 + quad * 4 + r;
        int t = row & 2047;
#pragma unroll
        for (int nt = 0; nt < 2; ++nt) {
          int dr = nt * 16 + l15;       // 0..31
          float c = cosb[t * 32 + dr], s = sinb[t * 32 + dr];
          float v1 = acc[mt][nt][r] + bb[nt];
          float v2 = acc[mt][nt + 2][r] + bb[nt + 2];
          unsigned w = pk_bf16_rnd((v1 * c - v2 * s) * scale, (v2 * c + v1 * s) * scale);
          *(unsigned*)(QK + (size_t)row * 2048 + headcol + 2 * dr) = w;
        }
      }
    }
  } else {                              // v: LDS transpose -> [bh][d][t], 128B row stores
    unsigned short* Tw = SMEM + wave * 4096;   // [d=64][8 units of 8 shorts], col = u^(d&7)
    const int hv = (headcol - 2048) >> 6;
    const int t0 = (m0 + wm) & 2047;
#pragma unroll
    for (int mt = 0; mt < 4; ++mt)
#pragma unroll
      for (int nt = 0; nt < 4; ++nt) {
        int d = nt * 16 + l15;
        uint2 w;
        w.x = pk_bf16_rnd(acc[mt][nt][0] + bb[nt], acc[mt][nt][1] + bb[nt]);
        w.y = pk_bf16_rnd(acc[mt][nt][2] + bb[nt], acc[mt][nt][3] + bb[nt]);
        int u = mt * 2 + (quad >> 1);
        *(uint2*)(Tw + d * 64 + ((u ^ (d & 7)) * 8) + (quad & 1) * 4) = w;
      }
    unsigned short* vbase = Vt + ((size_t)((b * 16 + hv) * 64)) * 2048 + t0;
#pragma unroll
    for (int dp = 0; dp < 8; ++dp) {
      int d = dp * 8 + (lane >> 3);
      int u = lane & 7;
      uint4 w4 = *(uint4*)(Tw + d * 64 + ((u ^ (d & 7)) * 8));
      *(uint4*)(vbase + (size_t)d * 2048 + u * 8) = w4;
    }
  }
}

// ---------------- bf16 GEMM, 64(M)x128(N) tile (out-projection) ----------------
__global__ __launch_bounds__(256, 2) void gemm64(
    const unsigned short* __restrict__ A, const unsigned short* __restrict__ Bt,
    const float* __restrict__ bias, float* __restrict__ C, int M, int N, int K) {
  __shared__ alignas(16) unsigned short As[64 * 64];
  __shared__ alignas(16) unsigned short Bs[128 * 64];
  const int tid = threadIdx.x;
  const int lane = tid & 63, wave = tid >> 6;
  const int l15 = lane & 15, quad = lane >> 4;
  const int m0 = blockIdx.y * 64, n0 = blockIdx.x * 128;
  const int wm = (wave & 1) * 32, wn = (wave >> 1) * 64;

  f32x4 acc[2][4];
#pragma unroll
  for (int i = 0; i < 2; i++)
#pragma unroll
    for (int j = 0; j < 4; j++)
#pragma unroll
      for (int r = 0; r < 4; r++) acc[i][j][r] = 0.f;

  const int nkt = K >> 6;
  for (int kt = 0; kt < nkt; ++kt) {
    __syncthreads();
#pragma unroll
    for (int i = 0; i < 2; ++i) {
      int u = i * 256 + tid;
      int row = u >> 3;
      int kcg = (u & 7) ^ (row & 7);
      g2l16(A + (size_t)(m0 + row) * K + (kt << 6) + (kcg << 3), As + u * 8);
    }
#pragma unroll
    for (int i = 0; i < 4; ++i) {
      int u = i * 256 + tid;
      int row = u >> 3;
      int kcg = (u & 7) ^ (row & 7);
      g2l16(Bt + (size_t)(n0 + row) * K + (kt << 6) + (kcg << 3), Bs + u * 8);
    }
    __syncthreads();
#pragma unroll
    for (int ks = 0; ks < 2; ++ks) {
      const int kc = ks * 4 + quad;
      bf16x8 af[2], bfr[4];
#pragma unroll
      for (int t = 0; t < 2; ++t) {
        int mrow = wm + t * 16 + l15;
        af[t] = *(const bf16x8*)(As + (mrow * 8 + (kc ^ (mrow & 7))) * 8);
      }
#pragma unroll
      for (int t = 0; t < 4; ++t) {
        int nrow = wn + t * 16 + l15;
        bfr[t] = *(const bf16x8*)(Bs + (nrow * 8 + (kc ^ (nrow & 7))) * 8);
      }
#pragma unroll
      for (int mt = 0; mt < 2; ++mt)
#pragma unroll
        for (int nt = 0; nt < 4; ++nt)
          acc[mt][nt] = __builtin_amdgcn_mfma_f32_16x16x32_bf16(af[mt], bfr[nt], acc[mt][nt], 0, 0, 0);
    }
  }
#pragma unroll
  for (int mt = 0; mt < 2; ++mt)
#pragma unroll
    for (int nt = 0; nt < 4; ++nt) {
      int col = n0 + wn + nt * 16 + l15;
      int rowb = m0 + wm + mt * 16 + quad * 4;
      float b = bias[col];
#pragma unroll
      for (int r = 0; r < 4; ++r)
        C[(size_t)(rowb + r) * N + col] = acc[mt][nt][r] + b;
    }
}

// -------- flash attention: single-pass, wave-private LDS P, all-x32 MFMA --------
// grid (x = bh [32], y = qb [16]); 4 waves x 32q; 16 key-tiles of 128.
// p = 2^(q.k*0.125*log2e - 12); P^T stored per-wave in LDS [q][key] with even-bit
// XOR swizzle (b128-aligned); PV = V^T @ P^T with 16x16x32 MFMA (32 vs 64 instrs).
// bh fastest in grid => all qb-blocks of one bh share an XCD (K/V L2 reuse).
__global__ __launch_bounds__(256, 2) void flash_attn(const unsigned short* __restrict__ QK,
                                                     const unsigned short* __restrict__ Vt,
                                                     unsigned short* __restrict__ O) {
  __shared__ alignas(16) unsigned short Ks[128 * 64];   // [key][d], swizzled 16B units
  __shared__ alignas(16) unsigned short Vs[64 * 128];   // [d][key], swizzled 16B units
  __shared__ alignas(16) unsigned short Ps[4 * 32 * 128]; // per-wave P^T [q][key]
  const int tid = threadIdx.x, lane = tid & 63, wave = tid >> 6;
  const int l15 = lane & 15, quad = lane >> 4;
  const int bh = blockIdx.x, qb = blockIdx.y;
  const int b = bh >> 4, h = bh & 15;
  const int q0 = qb * 128 + wave * 32;
  unsigned short* Pw = Ps + wave * 4096;
  // Q frags (B-operand of S^T): n=l15 -> q, k position = ks*32+quad*8+j
  bf16x8 qf[2][2];
#pragma unroll
  for (int ks = 0; ks < 2; ++ks)
#pragma unroll
    for (int qg = 0; qg < 2; ++qg)
      qf[ks][qg] = *(const bf16x8*)(QK + (size_t)(b * 2048 + q0 + qg * 16 + l15) * 2048 +
                                    h * 64 + ks * 32 + quad * 8);
  f32x4 o[2][4];
#pragma unroll
  for (int qg = 0; qg < 2; qg++)
#pragma unroll
    for (int nt = 0; nt < 4; nt++)
#pragma unroll
      for (int r = 0; r < 4; r++) o[qg][nt][r] = 0.f;
  float li[2] = {0.f, 0.f};
  const f32x4 negb = {-12.f, -12.f, -12.f, -12.f};

  for (int kb = 0; kb < 16; ++kb) {
    __syncthreads();
#pragma unroll
    for (int i = 0; i < 4; ++i) {
      int u = i * 256 + tid;
      int krow = u >> 3;
      int kcg = (u & 7) ^ (krow & 7);
      g2l16(QK + (size_t)(b * 2048 + kb * 128 + krow) * 2048 + 1024 + h * 64 + kcg * 8,
            Ks + u * 8);
      int vrow = u >> 4;
      int vcg = (u & 15) ^ (vrow & 7);
      g2l16(Vt + ((size_t)bh * 64 + vrow) * 2048 + kb * 128 + vcg * 8, Vs + u * 8);
    }
    __syncthreads();
    // S^T[key][q] - 12: A=K (m=key), B=Q^T. C-layout: row=key(quad*4+r), col=q(l15)
    f32x4 sacc[2][8];
#pragma unroll
    for (int ks = 0; ks < 2; ++ks) {
      const int kc = ks * 4 + quad;
#pragma unroll
      for (int mt = 0; mt < 8; ++mt) {
        int key = mt * 16 + l15;
        bf16x8 kf = *(const bf16x8*)(Ks + (key * 8 + (kc ^ (key & 7))) * 8);
        if (ks == 0) {
          sacc[0][mt] = __builtin_amdgcn_mfma_f32_16x16x32_bf16(kf, qf[0][0], negb, 0, 0, 0);
          sacc[1][mt] = __builtin_amdgcn_mfma_f32_16x16x32_bf16(kf, qf[0][1], negb, 0, 0, 0);
        } else {
          sacc[0][mt] = __builtin_amdgcn_mfma_f32_16x16x32_bf16(kf, qf[1][0], sacc[0][mt], 0, 0, 0);
          sacc[1][mt] = __builtin_amdgcn_mfma_f32_16x16x32_bf16(kf, qf[1][1], sacc[1][mt], 0, 0, 0);
        }
      }
    }
    // p = exp2(sacc) -> pack bf16 -> wave-private LDS P^T[q=32][key=128]
    // 8B unit = 4 keys; swizzled slot = unit ^ ((row&15)<<1)  (bit0 kept => b128 pairs stay aligned)
#pragma unroll
    for (int qg = 0; qg < 2; ++qg) {
      const int row = qg * 16 + l15;
      const int sw = (row & 15) << 1;
      float psum = 0.f;
#pragma unroll
      for (int mt = 0; mt < 8; ++mt) {
        float p0 = EXP2(sacc[qg][mt][0]);
        float p1 = EXP2(sacc[qg][mt][1]);
        float p2 = EXP2(sacc[qg][mt][2]);
        float p3 = EXP2(sacc[qg][mt][3]);
        psum += (p0 + p1) + (p2 + p3);
        uint2 w;
        w.x = pk_bf16_trunc(p0, p1);
        w.y = pk_bf16_trunc(p2, p3);
        int su = (mt * 4 + quad) ^ sw;       // unit = key/4 = mt*4+quad
        *(uint2*)(Pw + row * 128 + su * 4) = w;
      }
      li[qg] += psum;
    }
    // O^T += V^T @ P^T, 16x16x32: A=V^T (m=d=l15, k=quad*8+j), B=P^T (n=q=l15, k=quad*8+j)
#pragma unroll
    for (int c = 0; c < 4; ++c) {            // key chunk of 32
      bf16x8 vv[4];
#pragma unroll
      for (int nt = 0; nt < 4; ++nt) {
        int dd = nt * 16 + l15;
        int vu = (c * 4 + quad) ^ (dd & 7);  // 16B unit within Vs row
        vv[nt] = *(const bf16x8*)(Vs + dd * 128 + vu * 8);
      }
#pragma unroll
      for (int qg = 0; qg < 2; ++qg) {
        int prow = qg * 16 + l15;
        int pu = (c * 8 + quad * 2) ^ ((prow & 15) << 1);   // even 8B-unit index
        bf16x8 pf = *(const bf16x8*)(Pw + prow * 128 + pu * 4);
#pragma unroll
        for (int nt = 0; nt < 4; ++nt)
          o[qg][nt] = __builtin_amdgcn_mfma_f32_16x16x32_bf16(vv[nt], pf, o[qg][nt], 0, 0, 0);
      }
    }
  }
  // epilogue: O^T layout d = nt*16+quad*4+r, q = qg*16+l15; pack 4 d per 8B store
#pragma unroll
  for (int qg = 0; qg < 2; ++qg) {
    li[qg] += __shfl_xor(li[qg], 16);
    li[qg] += __shfl_xor(li[qg], 32);
    float inv = 1.001953125f / li[qg];   // compensate P truncation bias
    size_t rowb = (size_t)(b * 2048 + q0 + qg * 16 + l15) * 1024 + h * 64;
#pragma unroll
    for (int nt = 0; nt < 4; ++nt) {
      uint2 w;
      w.x = pk_bf16_rnd(o[qg][nt][0] * inv, o[qg][nt][1] * inv);
      w.y = pk_bf16_rnd(o[qg][nt][2] * inv, o[qg][nt][3] * inv);
      *(uint2*)(O + rowb + nt * 16 + quad * 4) = w;
    }
  }
}

extern "C" void kernel_launch(void* const* d_in, const int* in_sizes, int n_in,
                              void* d_out, int out_size, void* d_ws, size_t ws_size,
                              hipStream_t stream) {
  const float* x    = (const float*)d_in[0];
  const float* Wqkv = (const float*)d_in[1];
  const float* bqkv = (const float*)d_in[2];
  const float* Wout = (const float*)d_in[3];
  const float* bout = (const float*)d_in[4];
  float* out = (float*)d_out;
  char* ws = (char*)d_ws;
  // workspace map (~51 MB)
  float*          COS  = (float*)(ws + 0);                   // 262144
  float*          SIN  = (float*)(ws + 262144);              // 262144
  unsigned short* A1   = (unsigned short*)(ws + 524288);     // 8388608
  unsigned short* W1t  = (unsigned short*)(ws + 8912896);    // 6291456
  unsigned short* W2t  = (unsigned short*)(ws + 15204352);   // 2097152
  unsigned short* QK   = (unsigned short*)(ws + 17301504);   // 16777216  q|k roped (paired layout)
  unsigned short* VT   = (unsigned short*)(ws + 34078720);   // 8388608   v^T [32][64][2048]
  unsigned short* A2   = (unsigned short*)(ws + 42467328);   // 8388608   attn bf16

  prep<<<5376, 256, 0, stream>>>(x, Wqkv, Wout, COS, SIN, A1, W1t, W2t);
  gemm_qkv<<<dim3(24, 32), 256, 0, stream>>>(A1, W1t, bqkv, COS, SIN, QK, VT);
  flash_attn<<<dim3(32, 16), 256, 0, stream>>>(QK, VT, A2);
  gemm64<<<dim3(8, 64), 256, 0, stream>>>(A2, W2t, bout, out, 4096, 1024, 1024);
}